// Round 3
// baseline (538.334 us; speedup 1.0000x reference)
//
#include <hip/hip_runtime.h>
#include <hip/hip_bf16.h>

#define DI __device__ __forceinline__

namespace {

constexpr int Bc = 2, Tc = 2048, Dc = 2048, Hc = 32, KVHc = 8, HDc = 64;
constexpr int NQKV = Hc * HDc + 2 * KVHc * HDc;  // 3072

typedef __bf16 bf16x8 __attribute__((ext_vector_type(8)));
typedef unsigned short u16x8 __attribute__((ext_vector_type(8)));
typedef float f32x4 __attribute__((ext_vector_type(4)));

union FragU { u16x8 u; bf16x8 b; };

DI float bits2f(unsigned int u) {
  union { unsigned int i; float f; } v; v.i = u << 16; return v.f;
}
DI unsigned short f2bits(float f) {
  __hip_bfloat16 h = __float2bfloat16(f);
  return *reinterpret_cast<unsigned short*>(&h);
}

DI void store_out(float* p, float v) { *p = v; }
DI void store_out(__hip_bfloat16* p, float v) { *p = __float2bfloat16(v); }

typedef __attribute__((address_space(1))) void gv_t;
typedef __attribute__((address_space(3))) void lv_t;

// Stage TOTB bytes (tile of rows with ROWB bytes/row, global row stride row_stride_b)
// into LDS row-major-contiguous, via global_load_lds width=16.
// LDS dest is wave-uniform base + lane*16 (HW semantics).
template<int ROWB, int TOTB>
DI void stage_tile(const char* g, long long row_stride_b, char* lds) {
  const int tid = threadIdx.x;
  const int wid = tid >> 6, lane = tid & 63;
#pragma unroll
  for (int it = 0; it < TOTB / 4096; ++it) {
    int off = it * 4096 + wid * 1024 + lane * 16;
    int row = off / ROWB;
    int colb = off % ROWB;
    const char* gp = g + (long long)row * row_stride_b + colb;
    char* lp = lds + it * 4096 + wid * 1024;  // wave-uniform
    __builtin_amdgcn_global_load_lds((gv_t*)gp, (lv_t*)lp, 16, 0, 0);
  }
}

// ---------------- f32 -> bf16 elementwise convert (8 elems/thread) ----------------
__global__ __launch_bounds__(256) void cvt_f32_bf16(
    const float* __restrict__ in, __hip_bfloat16* __restrict__ out) {
  const long long i = ((long long)blockIdx.x * 256 + threadIdx.x) * 8;
  const float4 a = *(const float4*)(in + i);
  const float4 b = *(const float4*)(in + i + 4);
  u16x8 r;
  r[0] = f2bits(a.x); r[1] = f2bits(a.y); r[2] = f2bits(a.z); r[3] = f2bits(a.w);
  r[4] = f2bits(b.x); r[5] = f2bits(b.y); r[6] = f2bits(b.z); r[7] = f2bits(b.w);
  *(u16x8*)((unsigned short*)out + i) = r;
}

// ------------- 64x64 tiled transpose + f32->bf16 convert: out[c][r] = in[r][c] -------------
__global__ __launch_bounds__(256) void transpose_cvt_kernel(
    const float* __restrict__ in, __hip_bfloat16* __restrict__ out, int R, int C) {
  __shared__ unsigned short tile[64][65];
  const int c0 = blockIdx.x * 64, r0 = blockIdx.y * 64;
  const int tid = threadIdx.x;
  const int rr = tid >> 2, seg = (tid & 3) * 16;
  const float* src = in + (long long)(r0 + rr) * C + c0 + seg;
#pragma unroll
  for (int i = 0; i < 16; ++i) tile[rr][seg + i] = f2bits(src[i]);
  __syncthreads();
  unsigned short* dst = (unsigned short*)out + (long long)(c0 + rr) * R + r0 + seg;
#pragma unroll
  for (int i = 0; i < 16; ++i) dst[i] = tile[seg + i][rr];
}

// ---------------- 64x64 tiled bf16 transpose: out[c][r] = in[r][c] ----------------
__global__ __launch_bounds__(256) void transpose_kernel(
    const __hip_bfloat16* __restrict__ in, __hip_bfloat16* __restrict__ out,
    int R, int C) {
  __shared__ unsigned short tile[64][65];
  const long long slice = (long long)R * C;
  const unsigned short* ip = (const unsigned short*)in + (long long)blockIdx.z * slice;
  unsigned short* op = (unsigned short*)out + (long long)blockIdx.z * slice;
  const int c0 = blockIdx.x * 64, r0 = blockIdx.y * 64;
  const int tid = threadIdx.x;
  const int rr = tid >> 2, seg = (tid & 3) * 16;
  const unsigned short* src = ip + (long long)(r0 + rr) * C + c0 + seg;
#pragma unroll
  for (int i = 0; i < 16; ++i) tile[rr][seg + i] = src[i];
  __syncthreads();
  unsigned short* dst = op + (long long)(c0 + rr) * R + r0 + seg;
#pragma unroll
  for (int i = 0; i < 16; ++i) dst[i] = tile[seg + i][rr];
}

// ---------------- GEMM: C[m][n] = sum_k A[m][k]*Bt[n][k] (+bias[n]) ----------------
// A: MxK row-major bf16, Bt: NxK row-major bf16 (B pre-transposed), C: MxN (OT).
// 128x128 tile, BK=32, 4 waves in 2x2, 4x4 16x16x32 MFMAs per wave.
template <typename OT>
__global__ __launch_bounds__(256) void gemm_bt(
    const __hip_bfloat16* __restrict__ A, const __hip_bfloat16* __restrict__ Bt,
    const float* __restrict__ bias, OT* __restrict__ C, int M, int N, int K) {
  __shared__ __align__(16) char As[8192];  // 128 x 32 bf16
  __shared__ __align__(16) char Bs[8192];
  const int n0 = blockIdx.x * 128;
  const int m0 = blockIdx.y * 128;
  const int tid = threadIdx.x;
  const int wid = tid >> 6, lane = tid & 63;
  const int wm = (wid >> 1) * 64, wn = (wid & 1) * 64;
  const int l15 = lane & 15, quad = lane >> 4;

  f32x4 acc[4][4] = {};

  const int nk = K >> 5;
  for (int kt = 0; kt < nk; ++kt) {
    __syncthreads();  // protect LDS reuse from previous iteration's readers
    stage_tile<64, 8192>((const char*)(A + (long long)m0 * K + kt * 32), (long long)K * 2, As);
    stage_tile<64, 8192>((const char*)(Bt + (long long)n0 * K + kt * 32), (long long)K * 2, Bs);
    __syncthreads();  // drains vmcnt(0): staging complete

    FragU a[4], b[4];
#pragma unroll
    for (int mt = 0; mt < 4; ++mt)
      a[mt].u = *(const u16x8*)(As + ((wm + mt * 16 + l15) * 32 + quad * 8) * 2);
#pragma unroll
    for (int nt = 0; nt < 4; ++nt)
      b[nt].u = *(const u16x8*)(Bs + ((wn + nt * 16 + l15) * 32 + quad * 8) * 2);
#pragma unroll
    for (int mt = 0; mt < 4; ++mt)
#pragma unroll
      for (int nt = 0; nt < 4; ++nt)
        acc[mt][nt] = __builtin_amdgcn_mfma_f32_16x16x32_bf16(a[mt].b, b[nt].b, acc[mt][nt], 0, 0, 0);
  }

#pragma unroll
  for (int nt = 0; nt < 4; ++nt) {
    const int col = n0 + wn + nt * 16 + l15;
    const float bv = bias ? bias[col] : 0.f;
#pragma unroll
    for (int mt = 0; mt < 4; ++mt) {
#pragma unroll
      for (int r = 0; r < 4; ++r) {
        const int row = m0 + wm + mt * 16 + quad * 4 + r;
        store_out(C + (long long)row * N + col, acc[mt][nt][r] + bv);
      }
    }
  }
}

// ---------------- RoPE + reshape ----------------
// qkv (B*T, 3072) bf16 -> Q (B,H,T,64) roped, K (B,KVH,T,64) roped, V (B,KVH,T,64) raw.
// cos/sin read as f32.
__global__ __launch_bounds__(256) void rope_reshape(
    const __hip_bfloat16* __restrict__ qkv, const float* __restrict__ cosb,
    const float* __restrict__ sinb, __hip_bfloat16* __restrict__ Qo,
    __hip_bfloat16* __restrict__ Ko, __hip_bfloat16* __restrict__ Vo) {
  const int row = blockIdx.x;            // b*T + t
  const int b = row / Tc, t = row % Tc;
  const unsigned short* src = (const unsigned short*)qkv + (long long)row * NQKV;
  const float* cb = cosb + t * 32;
  const float* sb = sinb + t * 32;
  unsigned short* Qp = (unsigned short*)Qo;
  unsigned short* Kp = (unsigned short*)Ko;
  unsigned short* Vp = (unsigned short*)Vo;
#pragma unroll
  for (int rep = 0; rep < 6; ++rep) {
    const int pid = rep * 256 + (int)threadIdx.x;  // pair id, 0..1535
    const int e = pid * 2;
    const unsigned int pr = *(const unsigned int*)(src + e);
    const float xe = bits2f(pr & 0xffffu);
    const float xo = bits2f(pr >> 16);
    if (e < Hc * HDc) {                         // Q section
      const int hh = e >> 6, d = e & 63, ii = d >> 1;
      const float c = cb[ii], s = sb[ii];
      const unsigned int pk = (unsigned int)f2bits(xe * c - xo * s) |
                              ((unsigned int)f2bits(xe * s + xo * c) << 16);
      const long long idx = (((long long)b * Hc + hh) * Tc + t) * HDc + d;
      *(unsigned int*)(Qp + idx) = pk;
    } else if (e < Hc * HDc + KVHc * HDc) {     // K section
      const int e2 = e - Hc * HDc;
      const int kh = e2 >> 6, d = e2 & 63, ii = d >> 1;
      const float c = cb[ii], s = sb[ii];
      const unsigned int pk = (unsigned int)f2bits(xe * c - xo * s) |
                              ((unsigned int)f2bits(xe * s + xo * c) << 16);
      const long long idx = (((long long)b * KVHc + kh) * Tc + t) * HDc + d;
      *(unsigned int*)(Kp + idx) = pk;
    } else {                                    // V section (no rope)
      const int e2 = e - (Hc * HDc + KVHc * HDc);
      const int kh = e2 >> 6, d = e2 & 63;
      const long long idx = (((long long)b * KVHc + kh) * Tc + t) * HDc + d;
      *(unsigned int*)(Vp + idx) = pr;
    }
  }
}

// ---------------- Causal flash attention ----------------
// Q (B,H,T,64), K (B,KVH,T,64), Vt (B,KVH,64,T) -> Out (B,T,H*64), all bf16.
// Block = 64 q rows of one (b,h); 4 waves, each a 16-row strip. Online softmax.
__global__ __launch_bounds__(256) void attn_kernel(
    const __hip_bfloat16* __restrict__ Q, const __hip_bfloat16* __restrict__ K,
    const __hip_bfloat16* __restrict__ Vt, __hip_bfloat16* __restrict__ Out) {
  __shared__ __align__(16) char Qs[8192];            // 64 q x 64 hd
  __shared__ __align__(16) char Ks[8192];            // 64 kv x 64 hd
  __shared__ __align__(16) char Vs[8192];            // 64 hd x 64 kv (from global V^T)
  __shared__ __align__(16) unsigned short Ps[4][16 * 64];  // per-wave P strip

  const int qt = blockIdx.x, h = blockIdx.y, b = blockIdx.z;
  const int kvh = h >> 2;  // G = 4
  const int tid = threadIdx.x, wid = tid >> 6, lane = tid & 63;
  const int l15 = lane & 15, quad = lane >> 4;
  const int q0 = qt * 64;

  const char* Qg = (const char*)(Q + (((long long)b * Hc + h) * Tc + q0) * HDc);
  const char* Kg = (const char*)(K + (((long long)b * KVHc + kvh) * Tc) * HDc);
  const char* Vg = (const char*)(Vt + (((long long)b * KVHc + kvh) * HDc) * Tc);

  stage_tile<128, 8192>(Qg, 128, Qs);  // contiguous rows (stride == row bytes)

  f32x4 Oacc[4] = {};
  float m_i[4], l_i[4];
#pragma unroll
  for (int r = 0; r < 4; ++r) { m_i[r] = -1e30f; l_i[r] = 0.f; }

  unsigned short* Pw = &Ps[wid][0];

  for (int j = 0; j <= qt; ++j) {
    __syncthreads();
    stage_tile<128, 8192>(Kg + (long long)j * 64 * 128, 128, Ks);
    stage_tile<128, 8192>(Vg + (long long)j * 128, (long long)Tc * 2, Vs);
    __syncthreads();

    // S strip (16 q x 64 kv) = Q K^T
    FragU qa[2];
#pragma unroll
    for (int ks = 0; ks < 2; ++ks)
      qa[ks].u = *(const u16x8*)(Qs + ((wid * 16 + l15) * 64 + ks * 32 + quad * 8) * 2);

    f32x4 Sacc[4] = {};
#pragma unroll
    for (int nt = 0; nt < 4; ++nt) {
#pragma unroll
      for (int ks = 0; ks < 2; ++ks) {
        FragU kb;
        kb.u = *(const u16x8*)(Ks + ((nt * 16 + l15) * 64 + ks * 32 + quad * 8) * 2);
        Sacc[nt] = __builtin_amdgcn_mfma_f32_16x16x32_bf16(qa[ks].b, kb.b, Sacc[nt], 0, 0, 0);
      }
    }

    // scale + causal mask (only diagonal tile needs masking)
    const bool diag = (j == qt);
    float sv[4][4];
#pragma unroll
    for (int nt = 0; nt < 4; ++nt)
#pragma unroll
      for (int r = 0; r < 4; ++r) {
        float s = Sacc[nt][r] * 0.125f;
        if (diag && (nt * 16 + l15) > (wid * 16 + quad * 4 + r)) s = -1e30f;
        sv[nt][r] = s;
      }

    // online softmax; rows of a strip live within one 16-lane quad group
    float alpha_r[4], padd[4][4];
#pragma unroll
    for (int r = 0; r < 4; ++r) {
      float mx = fmaxf(fmaxf(sv[0][r], sv[1][r]), fmaxf(sv[2][r], sv[3][r]));
#pragma unroll
      for (int d = 1; d < 16; d <<= 1) mx = fmaxf(mx, __shfl_xor(mx, d, 64));
      const float mnew = fmaxf(m_i[r], mx);
      alpha_r[r] = __expf(m_i[r] - mnew);  // first iter: exp(-1e30-m) = 0
      m_i[r] = mnew;
      float sum = 0.f;
#pragma unroll
      for (int nt = 0; nt < 4; ++nt) {
        const float pe = __expf(sv[nt][r] - mnew);
        padd[nt][r] = pe;
        sum += pe;
      }
#pragma unroll
      for (int d = 1; d < 16; d <<= 1) sum += __shfl_xor(sum, d, 64);
      l_i[r] = l_i[r] * alpha_r[r] + sum;
    }

    // rescale O; write P (C-layout) to wave-private LDS strip as bf16
#pragma unroll
    for (int nt = 0; nt < 4; ++nt)
#pragma unroll
      for (int r = 0; r < 4; ++r) {
        Oacc[nt][r] *= alpha_r[r];
        Pw[(quad * 4 + r) * 64 + nt * 16 + l15] = f2bits(padd[nt][r]);
      }

    // PV: A = P (A-layout from LDS), B = V (k=kv contiguous since Vs is hd-major)
    FragU pa[2];
#pragma unroll
    for (int ks = 0; ks < 2; ++ks)
      pa[ks].u = *(const u16x8*)((const char*)Pw + (l15 * 64 + ks * 32 + quad * 8) * 2);
#pragma unroll
    for (int nt = 0; nt < 4; ++nt) {
#pragma unroll
      for (int ks = 0; ks < 2; ++ks) {
        FragU vb;
        vb.u = *(const u16x8*)(Vs + ((nt * 16 + l15) * 64 + ks * 32 + quad * 8) * 2);
        Oacc[nt] = __builtin_amdgcn_mfma_f32_16x16x32_bf16(pa[ks].b, vb.b, Oacc[nt], 0, 0, 0);
      }
    }
  }

  // epilogue: O / l -> (B, T, H*HD)
#pragma unroll
  for (int nt = 0; nt < 4; ++nt)
#pragma unroll
    for (int r = 0; r < 4; ++r) {
      const int t = q0 + wid * 16 + quad * 4 + r;
      const int col = h * 64 + nt * 16 + l15;
      Out[((long long)b * Tc + t) * Dc + col] = __float2bfloat16(Oacc[nt][r] / l_i[r]);
    }
}

}  // namespace

extern "C" void kernel_launch(void* const* d_in, const int* in_sizes, int n_in,
                              void* d_out, int out_size, void* d_ws, size_t ws_size,
                              hipStream_t stream) {
  // All inputs/outputs are FLOAT32 per the reference dtypes.
  const float* x_q  = (const float*)d_in[0];
  const float* Wqkv = (const float*)d_in[1];
  const float* Wout = (const float*)d_in[2];
  const float* bout = (const float*)d_in[3];
  const float* rc   = (const float*)d_in[4];
  const float* rs   = (const float*)d_in[5];
  float* out = (float*)d_out;

  // ---- Overlapping bf16 workspace arena (peak 54.6 MB; stream order makes reuse safe) ----
  constexpr size_t SZ_QKV   = (size_t)Bc * Tc * NQKV * 2;        // 25,165,824
  constexpr size_t SZ_XB    = (size_t)Bc * Tc * Dc * 2;          // 16,777,216
  constexpr size_t SZ_WQKVT = (size_t)NQKV * Dc * 2;             // 12,582,912
  constexpr size_t SZ_QB    = (size_t)Bc * Hc * Tc * HDc * 2;    // 16,777,216
  constexpr size_t SZ_KV    = (size_t)Bc * KVHc * Tc * HDc * 2;  //  4,194,304
  constexpr size_t SZ_AO    = (size_t)Bc * Tc * Dc * 2;          // 16,777,216
  // lifetimes: xb [C1,G1]; WqkvT [T1,G1]; qkv [G1,R]; Qb,Kb [R,A]; Vtmp [R,TV];
  //            Vt [TV,A]; AO [A,G2]; WoutT [T2,G2] (T2 launched after A).
  constexpr size_t OFF_QKV   = 0;                    //  0   .. 25.2M
  constexpr size_t OFF_XB    = SZ_QKV;               // 25.2 .. 41.9M
  constexpr size_t OFF_WQKVT = SZ_QKV + SZ_XB;       // 41.9 .. 54.6M
  constexpr size_t OFF_QB    = SZ_QKV;               // reuses xb (dead after G1)
  constexpr size_t OFF_KB    = OFF_QB + SZ_QB;       // reuses WqkvT head (dead after G1)
  constexpr size_t OFF_VTMP  = OFF_KB + SZ_KV;       // 46.1 .. 50.3M
  constexpr size_t OFF_VT    = 0;                    // reuses qkv (dead after R)
  constexpr size_t OFF_AO    = SZ_KV;                // 4.2 .. 21.0M (old qkv region)
  constexpr size_t OFF_WOUTT = OFF_AO + SZ_AO;       // 21.0 .. 29.4M (old Qb head, dead after A)

  char* w = (char*)d_ws;
  __hip_bfloat16* qkv   = (__hip_bfloat16*)(w + OFF_QKV);
  __hip_bfloat16* xb    = (__hip_bfloat16*)(w + OFF_XB);
  __hip_bfloat16* WqkvT = (__hip_bfloat16*)(w + OFF_WQKVT);
  __hip_bfloat16* Qb    = (__hip_bfloat16*)(w + OFF_QB);
  __hip_bfloat16* Kb    = (__hip_bfloat16*)(w + OFF_KB);
  __hip_bfloat16* Vtmp  = (__hip_bfloat16*)(w + OFF_VTMP);
  __hip_bfloat16* Vt    = (__hip_bfloat16*)(w + OFF_VT);
  __hip_bfloat16* AO    = (__hip_bfloat16*)(w + OFF_AO);
  __hip_bfloat16* WoutT = (__hip_bfloat16*)(w + OFF_WOUTT);

  // C1: x_q f32 -> bf16 (8.4M elems, 8/thread)
  cvt_f32_bf16<<<dim3((Bc * Tc * Dc) / (256 * 8)), 256, 0, stream>>>(x_q, xb);

  // T1: W_qkv (D,3072) f32 -> (3072,D) bf16
  transpose_cvt_kernel<<<dim3(NQKV / 64, Dc / 64), 256, 0, stream>>>(Wqkv, WqkvT, Dc, NQKV);

  // G1: qkv = x @ W_qkv  (bf16 out)
  gemm_bt<__hip_bfloat16><<<dim3(NQKV / 128, (Bc * Tc) / 128), 256, 0, stream>>>(
      xb, WqkvT, nullptr, qkv, Bc * Tc, NQKV, Dc);

  // R: split + rope + head-major layouts (Qb overwrites dead xb region)
  rope_reshape<<<dim3(Bc * Tc), 256, 0, stream>>>(qkv, rc, rs, Qb, Kb, Vtmp);

  // TV: V (B,KVH,T,64) -> V^T (B,KVH,64,T) (Vt overwrites dead qkv region head)
  transpose_kernel<<<dim3(HDc / 64, Tc / 64, Bc * KVHc), 256, 0, stream>>>(Vtmp, Vt, Tc, HDc);

  // A: flash attention (AO lands in dead qkv region)
  attn_kernel<<<dim3(Tc / 64, Hc, Bc), 256, 0, stream>>>(Qb, Kb, Vt, AO);

  // T2: W_out f32 -> W_out^T bf16 (overwrites dead Qb head; after A, stream-ordered)
  transpose_cvt_kernel<<<dim3(Dc / 64, Dc / 64), 256, 0, stream>>>(Wout, WoutT, Dc, Dc);

  // G2: out = AO @ W_out + b_out  (f32 out)
  gemm_bt<float><<<dim3(Dc / 128, (Bc * Tc) / 128), 256, 0, stream>>>(
      AO, WoutT, bout, out, Bc * Tc, Dc, Dc);
}

// Round 4
// 482.658 us; speedup vs baseline: 1.1154x; 1.1154x over previous
//
#include <hip/hip_runtime.h>
#include <hip/hip_bf16.h>

#define DI __device__ __forceinline__

namespace {

constexpr int Bc = 2, Tc = 2048, Dc = 2048, Hc = 32, KVHc = 8, HDc = 64;
constexpr int NQKV = Hc * HDc + 2 * KVHc * HDc;  // 3072

typedef __bf16 bf16x8 __attribute__((ext_vector_type(8)));
typedef unsigned short u16x8 __attribute__((ext_vector_type(8)));
typedef float f32x4 __attribute__((ext_vector_type(4)));

union FragU { u16x8 u; bf16x8 b; };

DI float bits2f(unsigned int u) {
  union { unsigned int i; float f; } v; v.i = u << 16; return v.f;
}
DI unsigned short f2bits(float f) {
  __hip_bfloat16 h = __float2bfloat16(f);
  return *reinterpret_cast<unsigned short*>(&h);
}

DI void store_out(float* p, float v) { *p = v; }
DI void store_out(__hip_bfloat16* p, float v) { *p = __float2bfloat16(v); }

typedef __attribute__((address_space(1))) void gv_t;
typedef __attribute__((address_space(3))) void lv_t;

// Stage TOTB bytes (tile rows of ROWB bytes, global row stride row_stride_b) into
// LDS via global_load_lds width=16. LDS dest is wave-uniform base + lane*16 (HW),
// so the optional XOR swizzle permutes the GLOBAL source chunk per lane instead:
// LDS slot (row, chunk k) holds global chunk k ^ (row&7)  [ROWB=128 only].
template<int ROWB, int TOTB, bool SWZ = false>
DI void stage_tile(const char* g, long long row_stride_b, char* lds) {
  const int tid = threadIdx.x;
  const int wid = tid >> 6, lane = tid & 63;
#pragma unroll
  for (int it = 0; it < TOTB / 4096; ++it) {
    int off = it * 4096 + wid * 1024 + lane * 16;
    int row = off / ROWB;
    int colb = off % ROWB;
    if (SWZ) colb ^= (row & 7) << 4;  // 16B-chunk XOR swizzle (ROWB=128)
    const char* gp = g + (long long)row * row_stride_b + colb;
    char* lp = lds + it * 4096 + wid * 1024;  // wave-uniform
    __builtin_amdgcn_global_load_lds((gv_t*)gp, (lv_t*)lp, 16, 0, 0);
  }
}

// ---------------- f32 -> bf16 elementwise convert (8 elems/thread) ----------------
__global__ __launch_bounds__(256) void cvt_f32_bf16(
    const float* __restrict__ in, __hip_bfloat16* __restrict__ out) {
  const long long i = ((long long)blockIdx.x * 256 + threadIdx.x) * 8;
  const float4 a = *(const float4*)(in + i);
  const float4 b = *(const float4*)(in + i + 4);
  u16x8 r;
  r[0] = f2bits(a.x); r[1] = f2bits(a.y); r[2] = f2bits(a.z); r[3] = f2bits(a.w);
  r[4] = f2bits(b.x); r[5] = f2bits(b.y); r[6] = f2bits(b.z); r[7] = f2bits(b.w);
  *(u16x8*)((unsigned short*)out + i) = r;
}

// ------------- 64x64 tiled transpose + f32->bf16 convert: out[c][r] = in[r][c] -------------
__global__ __launch_bounds__(256) void transpose_cvt_kernel(
    const float* __restrict__ in, __hip_bfloat16* __restrict__ out, int R, int C) {
  __shared__ unsigned short tile[64][65];
  const int c0 = blockIdx.x * 64, r0 = blockIdx.y * 64;
  const int tid = threadIdx.x;
  const int rr = tid >> 2, seg = (tid & 3) * 16;
  const float* src = in + (long long)(r0 + rr) * C + c0 + seg;
#pragma unroll
  for (int i = 0; i < 16; ++i) tile[rr][seg + i] = f2bits(src[i]);
  __syncthreads();
  unsigned short* dst = (unsigned short*)out + (long long)(c0 + rr) * R + r0 + seg;
#pragma unroll
  for (int i = 0; i < 16; ++i) dst[i] = tile[seg + i][rr];
}

// ---------------- 64x64 tiled bf16 transpose: out[c][r] = in[r][c] ----------------
__global__ __launch_bounds__(256) void transpose_kernel(
    const __hip_bfloat16* __restrict__ in, __hip_bfloat16* __restrict__ out,
    int R, int C) {
  __shared__ unsigned short tile[64][65];
  const long long slice = (long long)R * C;
  const unsigned short* ip = (const unsigned short*)in + (long long)blockIdx.z * slice;
  unsigned short* op = (unsigned short*)out + (long long)blockIdx.z * slice;
  const int c0 = blockIdx.x * 64, r0 = blockIdx.y * 64;
  const int tid = threadIdx.x;
  const int rr = tid >> 2, seg = (tid & 3) * 16;
  const unsigned short* src = ip + (long long)(r0 + rr) * C + c0 + seg;
#pragma unroll
  for (int i = 0; i < 16; ++i) tile[rr][seg + i] = src[i];
  __syncthreads();
  unsigned short* dst = op + (long long)(c0 + rr) * R + r0 + seg;
#pragma unroll
  for (int i = 0; i < 16; ++i) dst[i] = tile[seg + i][rr];
}

// ---------------- GEMM: C[m][n] = sum_k A[m][k]*Bt[n][k] (+bias[n]) ----------------
// A: MxK row-major bf16, Bt: NxK row-major bf16 (B pre-transposed), C: MxN (OT).
// 128x128 tile, BK=32, 4 waves in 2x2, 4x4 16x16x32 MFMAs per wave.
template <typename OT>
__global__ __launch_bounds__(256) void gemm_bt(
    const __hip_bfloat16* __restrict__ A, const __hip_bfloat16* __restrict__ Bt,
    const float* __restrict__ bias, OT* __restrict__ C, int M, int N, int K) {
  __shared__ __align__(16) char As[8192];  // 128 x 32 bf16
  __shared__ __align__(16) char Bs[8192];
  const int n0 = blockIdx.x * 128;
  const int m0 = blockIdx.y * 128;
  const int tid = threadIdx.x;
  const int wid = tid >> 6, lane = tid & 63;
  const int wm = (wid >> 1) * 64, wn = (wid & 1) * 64;
  const int l15 = lane & 15, quad = lane >> 4;

  f32x4 acc[4][4] = {};

  const int nk = K >> 5;
  for (int kt = 0; kt < nk; ++kt) {
    __syncthreads();  // protect LDS reuse from previous iteration's readers
    stage_tile<64, 8192>((const char*)(A + (long long)m0 * K + kt * 32), (long long)K * 2, As);
    stage_tile<64, 8192>((const char*)(Bt + (long long)n0 * K + kt * 32), (long long)K * 2, Bs);
    __syncthreads();  // drains vmcnt(0): staging complete

    FragU a[4], b[4];
#pragma unroll
    for (int mt = 0; mt < 4; ++mt)
      a[mt].u = *(const u16x8*)(As + ((wm + mt * 16 + l15) * 32 + quad * 8) * 2);
#pragma unroll
    for (int nt = 0; nt < 4; ++nt)
      b[nt].u = *(const u16x8*)(Bs + ((wn + nt * 16 + l15) * 32 + quad * 8) * 2);
#pragma unroll
    for (int mt = 0; mt < 4; ++mt)
#pragma unroll
      for (int nt = 0; nt < 4; ++nt)
        acc[mt][nt] = __builtin_amdgcn_mfma_f32_16x16x32_bf16(a[mt].b, b[nt].b, acc[mt][nt], 0, 0, 0);
  }

#pragma unroll
  for (int nt = 0; nt < 4; ++nt) {
    const int col = n0 + wn + nt * 16 + l15;
    const float bv = bias ? bias[col] : 0.f;
#pragma unroll
    for (int mt = 0; mt < 4; ++mt) {
#pragma unroll
      for (int r = 0; r < 4; ++r) {
        const int row = m0 + wm + mt * 16 + quad * 4 + r;
        store_out(C + (long long)row * N + col, acc[mt][nt][r] + bv);
      }
    }
  }
}

// ---------------- RoPE + reshape ----------------
// qkv (B*T, 3072) bf16 -> Q (B,H,T,64) roped*SCL, K (B,KVH,T,64) roped, V raw.
// SCL = (1/sqrt(64)) * log2(e) folded into Q so attention uses exp2.
__global__ __launch_bounds__(256) void rope_reshape(
    const __hip_bfloat16* __restrict__ qkv, const float* __restrict__ cosb,
    const float* __restrict__ sinb, __hip_bfloat16* __restrict__ Qo,
    __hip_bfloat16* __restrict__ Ko, __hip_bfloat16* __restrict__ Vo) {
  constexpr float SCL = 0.125f * 1.44269504088896f;
  const int row = blockIdx.x;            // b*T + t
  const int b = row / Tc, t = row % Tc;
  const unsigned short* src = (const unsigned short*)qkv + (long long)row * NQKV;
  const float* cb = cosb + t * 32;
  const float* sb = sinb + t * 32;
  unsigned short* Qp = (unsigned short*)Qo;
  unsigned short* Kp = (unsigned short*)Ko;
  unsigned short* Vp = (unsigned short*)Vo;
#pragma unroll
  for (int rep = 0; rep < 6; ++rep) {
    const int pid = rep * 256 + (int)threadIdx.x;  // pair id, 0..1535
    const int e = pid * 2;
    const unsigned int pr = *(const unsigned int*)(src + e);
    const float xe = bits2f(pr & 0xffffu);
    const float xo = bits2f(pr >> 16);
    if (e < Hc * HDc) {                         // Q section (scaled)
      const int hh = e >> 6, d = e & 63, ii = d >> 1;
      const float c = cb[ii], s = sb[ii];
      const unsigned int pk = (unsigned int)f2bits((xe * c - xo * s) * SCL) |
                              ((unsigned int)f2bits((xe * s + xo * c) * SCL) << 16);
      const long long idx = (((long long)b * Hc + hh) * Tc + t) * HDc + d;
      *(unsigned int*)(Qp + idx) = pk;
    } else if (e < Hc * HDc + KVHc * HDc) {     // K section
      const int e2 = e - Hc * HDc;
      const int kh = e2 >> 6, d = e2 & 63, ii = d >> 1;
      const float c = cb[ii], s = sb[ii];
      const unsigned int pk = (unsigned int)f2bits(xe * c - xo * s) |
                              ((unsigned int)f2bits(xe * s + xo * c) << 16);
      const long long idx = (((long long)b * KVHc + kh) * Tc + t) * HDc + d;
      *(unsigned int*)(Kp + idx) = pk;
    } else {                                    // V section (no rope)
      const int e2 = e - (Hc * HDc + KVHc * HDc);
      const int kh = e2 >> 6, d = e2 & 63;
      const long long idx = (((long long)b * KVHc + kh) * Tc + t) * HDc + d;
      *(unsigned int*)(Vp + idx) = pr;
    }
  }
}

// ---------------- Causal flash attention (swizzled LDS + K/V double-buffer) ----------------
// Q (B,H,T,64) pre-scaled, K (B,KVH,T,64), Vt (B,KVH,64,T) -> Out (B,T,H*64), bf16.
// Block = 64 q rows of one (b,h); 4 waves, each a 16-row strip. Online softmax (base 2).
// LDS: KB[2] (Q staged into KB[1] first), VB[2], per-wave P strip. One barrier per tile.
__global__ __launch_bounds__(256) void attn_kernel(
    const __hip_bfloat16* __restrict__ Q, const __hip_bfloat16* __restrict__ K,
    const __hip_bfloat16* __restrict__ Vt, __hip_bfloat16* __restrict__ Out) {
  __shared__ __align__(16) char KB[2][8192];               // 64 kv x 64 hd (swizzled)
  __shared__ __align__(16) char VB[2][8192];               // 64 hd x 64 kv (swizzled)
  __shared__ __align__(16) unsigned short Ps[4][1024];     // per-wave 16 x 64 P (swizzled)

  const int qt = gridDim.x - 1 - blockIdx.x;  // longest blocks dispatched first
  const int h = blockIdx.y, b = blockIdx.z;
  const int kvh = h >> 2;  // G = 4
  const int tid = threadIdx.x, wid = tid >> 6, lane = tid & 63;
  const int l15 = lane & 15, quad = lane >> 4;
  const int sw = l15 & 7;                      // row&7 for all fragment rows (row ≡ l15 mod 16)
  const int q0 = qt * 64;

  const char* Qg = (const char*)(Q + (((long long)b * Hc + h) * Tc + q0) * HDc);
  const char* Kg = (const char*)(K + (((long long)b * KVHc + kvh) * Tc) * HDc);
  const char* Vg = (const char*)(Vt + (((long long)b * KVHc + kvh) * HDc) * Tc);

  // Stage Q (into KB[1]) and tile 0; one drain.
  stage_tile<128, 8192, true>(Qg, 128, KB[1]);
  stage_tile<128, 8192, true>(Kg, 128, KB[0]);
  stage_tile<128, 8192, true>(Vg, (long long)Tc * 2, VB[0]);
  __syncthreads();

  // Hoist Q fragments (loop-invariant). row = wid*16 + l15.
  FragU qa[2];
#pragma unroll
  for (int ks = 0; ks < 2; ++ks) {
    const int row = wid * 16 + l15;
    qa[ks].u = *(const u16x8*)(KB[1] + row * 128 + ((((ks << 2) | quad) ^ sw) << 4));
  }
  __syncthreads();  // all waves read Q before prefetch j=1 overwrites KB[1]

  f32x4 Oacc[4] = {};
  float m_i[4], l_i[4];
#pragma unroll
  for (int r = 0; r < 4; ++r) { m_i[r] = -1e30f; l_i[r] = 0.f; }

  unsigned short* Pw = &Ps[wid][0];

  for (int j = 0; j <= qt; ++j) {
    const int cur = j & 1;
    if (j < qt) {  // prefetch j+1; drained by this iteration's end barrier
      stage_tile<128, 8192, true>(Kg + (long long)(j + 1) * 8192, 128, KB[cur ^ 1]);
      stage_tile<128, 8192, true>(Vg + (long long)(j + 1) * 128, (long long)Tc * 2, VB[cur ^ 1]);
    }
    const char* Kc = KB[cur];
    const char* Vc = VB[cur];

    // S strip (16 q x 64 kv) = Q K^T  (Q pre-scaled by 0.125*log2e)
    f32x4 Sacc[4] = {};
#pragma unroll
    for (int nt = 0; nt < 4; ++nt) {
#pragma unroll
      for (int ks = 0; ks < 2; ++ks) {
        const int row = nt * 16 + l15;
        FragU kb;
        kb.u = *(const u16x8*)(Kc + row * 128 + ((((ks << 2) | quad) ^ sw) << 4));
        Sacc[nt] = __builtin_amdgcn_mfma_f32_16x16x32_bf16(qa[ks].b, kb.b, Sacc[nt], 0, 0, 0);
      }
    }

    // causal mask (diagonal tile only); values are log2-scaled logits
    const bool diag = (j == qt);
    float sv[4][4];
#pragma unroll
    for (int nt = 0; nt < 4; ++nt)
#pragma unroll
      for (int r = 0; r < 4; ++r) {
        float s = Sacc[nt][r];
        if (diag && (nt * 16 + l15) > (wid * 16 + quad * 4 + r)) s = -1e30f;
        sv[nt][r] = s;
      }

    // online softmax in base 2; rows live within one 16-lane quad group
    float alpha_r[4], padd[4][4];
#pragma unroll
    for (int r = 0; r < 4; ++r) {
      float mx = fmaxf(fmaxf(sv[0][r], sv[1][r]), fmaxf(sv[2][r], sv[3][r]));
#pragma unroll
      for (int d = 1; d < 16; d <<= 1) mx = fmaxf(mx, __shfl_xor(mx, d, 64));
      const float mnew = fmaxf(m_i[r], mx);
      alpha_r[r] = exp2f(m_i[r] - mnew);  // first iter: exp2(-inf) = 0
      m_i[r] = mnew;
      float sum = 0.f;
#pragma unroll
      for (int nt = 0; nt < 4; ++nt) {
        const float pe = exp2f(sv[nt][r] - mnew);
        padd[nt][r] = pe;
        sum += pe;
      }
#pragma unroll
      for (int d = 1; d < 16; d <<= 1) sum += __shfl_xor(sum, d, 64);
      l_i[r] = l_i[r] * alpha_r[r] + sum;
    }

    // rescale O; write P (C-layout) to wave-private swizzled LDS strip
#pragma unroll
    for (int nt = 0; nt < 4; ++nt)
#pragma unroll
      for (int r = 0; r < 4; ++r) {
        Oacc[nt][r] *= alpha_r[r];
        const int prow = quad * 4 + r;
        const int chunk = (nt * 2 + (l15 >> 3)) ^ (prow & 7);
        Pw[prow * 64 + chunk * 8 + (l15 & 7)] = f2bits(padd[nt][r]);
      }

    // PV: A = P (A-layout, swizzled), B = V (kv-contiguous rows, swizzled)
    FragU pa[2];
#pragma unroll
    for (int ks = 0; ks < 2; ++ks)
      pa[ks].u = *(const u16x8*)((const char*)Pw + l15 * 128 + ((((ks << 2) | quad) ^ sw) << 4));
#pragma unroll
    for (int nt = 0; nt < 4; ++nt) {
#pragma unroll
      for (int ks = 0; ks < 2; ++ks) {
        const int row = nt * 16 + l15;
        FragU vb;
        vb.u = *(const u16x8*)(Vc + row * 128 + ((((ks << 2) | quad) ^ sw) << 4));
        Oacc[nt] = __builtin_amdgcn_mfma_f32_16x16x32_bf16(pa[ks].b, vb.b, Oacc[nt], 0, 0, 0);
      }
    }

    __syncthreads();  // waves done reading cur; drains prefetch into cur^1
  }

  // epilogue: O / l -> (B, T, H*HD)
#pragma unroll
  for (int nt = 0; nt < 4; ++nt)
#pragma unroll
    for (int r = 0; r < 4; ++r) {
      const int t = q0 + wid * 16 + quad * 4 + r;
      const int col = h * 64 + nt * 16 + l15;
      Out[((long long)b * Tc + t) * Dc + col] = __float2bfloat16(Oacc[nt][r] / l_i[r]);
    }
}

}  // namespace

extern "C" void kernel_launch(void* const* d_in, const int* in_sizes, int n_in,
                              void* d_out, int out_size, void* d_ws, size_t ws_size,
                              hipStream_t stream) {
  // All inputs/outputs are FLOAT32 per the reference dtypes.
  const float* x_q  = (const float*)d_in[0];
  const float* Wqkv = (const float*)d_in[1];
  const float* Wout = (const float*)d_in[2];
  const float* bout = (const float*)d_in[3];
  const float* rc   = (const float*)d_in[4];
  const float* rs   = (const float*)d_in[5];
  float* out = (float*)d_out;

  // ---- Overlapping bf16 workspace arena (peak 54.6 MB; stream order makes reuse safe) ----
  constexpr size_t SZ_QKV   = (size_t)Bc * Tc * NQKV * 2;        // 25,165,824
  constexpr size_t SZ_XB    = (size_t)Bc * Tc * Dc * 2;          // 16,777,216
  constexpr size_t SZ_QB    = (size_t)Bc * Hc * Tc * HDc * 2;    // 16,777,216
  constexpr size_t SZ_KV    = (size_t)Bc * KVHc * Tc * HDc * 2;  //  4,194,304
  constexpr size_t SZ_AO    = (size_t)Bc * Tc * Dc * 2;          // 16,777,216
  constexpr size_t OFF_QKV   = 0;                    //  0   .. 25.2M
  constexpr size_t OFF_XB    = SZ_QKV;               // 25.2 .. 41.9M
  constexpr size_t OFF_WQKVT = SZ_QKV + SZ_XB;       // 41.9 .. 54.6M
  constexpr size_t OFF_QB    = SZ_QKV;               // reuses xb (dead after G1)
  constexpr size_t OFF_KB    = OFF_QB + SZ_QB;       // reuses WqkvT head (dead after G1)
  constexpr size_t OFF_VTMP  = OFF_KB + SZ_KV;       // 46.1 .. 50.3M
  constexpr size_t OFF_VT    = 0;                    // reuses qkv (dead after R)
  constexpr size_t OFF_AO    = SZ_KV;                // 4.2 .. 21.0M (old qkv region)
  constexpr size_t OFF_WOUTT = OFF_AO + SZ_AO;       // 21.0 .. 29.4M (old Qb head, dead after A)

  char* w = (char*)d_ws;
  __hip_bfloat16* qkv   = (__hip_bfloat16*)(w + OFF_QKV);
  __hip_bfloat16* xb    = (__hip_bfloat16*)(w + OFF_XB);
  __hip_bfloat16* WqkvT = (__hip_bfloat16*)(w + OFF_WQKVT);
  __hip_bfloat16* Qb    = (__hip_bfloat16*)(w + OFF_QB);
  __hip_bfloat16* Kb    = (__hip_bfloat16*)(w + OFF_KB);
  __hip_bfloat16* Vtmp  = (__hip_bfloat16*)(w + OFF_VTMP);
  __hip_bfloat16* Vt    = (__hip_bfloat16*)(w + OFF_VT);
  __hip_bfloat16* AO    = (__hip_bfloat16*)(w + OFF_AO);
  __hip_bfloat16* WoutT = (__hip_bfloat16*)(w + OFF_WOUTT);

  // C1: x_q f32 -> bf16
  cvt_f32_bf16<<<dim3((Bc * Tc * Dc) / (256 * 8)), 256, 0, stream>>>(x_q, xb);

  // T1: W_qkv (D,3072) f32 -> (3072,D) bf16
  transpose_cvt_kernel<<<dim3(NQKV / 64, Dc / 64), 256, 0, stream>>>(Wqkv, WqkvT, Dc, NQKV);

  // G1: qkv = x @ W_qkv  (bf16 out)
  gemm_bt<__hip_bfloat16><<<dim3(NQKV / 128, (Bc * Tc) / 128), 256, 0, stream>>>(
      xb, WqkvT, nullptr, qkv, Bc * Tc, NQKV, Dc);

  // R: split + rope (+ Q pre-scale) + head-major layouts
  rope_reshape<<<dim3(Bc * Tc), 256, 0, stream>>>(qkv, rc, rs, Qb, Kb, Vtmp);

  // TV: V (B,KVH,T,64) -> V^T (B,KVH,64,T)
  transpose_kernel<<<dim3(HDc / 64, Tc / 64, Bc * KVHc), 256, 0, stream>>>(Vtmp, Vt, Tc, HDc);

  // A: flash attention
  attn_kernel<<<dim3(Tc / 64, Hc, Bc), 256, 0, stream>>>(Qb, Kb, Vt, AO);

  // T2: W_out f32 -> W_out^T bf16
  transpose_cvt_kernel<<<dim3(Dc / 64, Dc / 64), 256, 0, stream>>>(Wout, WoutT, Dc, Dc);

  // G2: out = AO @ W_out + b_out  (f32 out)
  gemm_bt<float><<<dim3(Dc / 128, (Bc * Tc) / 128), 256, 0, stream>>>(
      AO, WoutT, bout, out, Bc * Tc, Dc, Dc);
}

// Round 7
// 386.698 us; speedup vs baseline: 1.3921x; 1.2482x over previous
//
#include <hip/hip_runtime.h>
#include <hip/hip_bf16.h>

#define DI __device__ __forceinline__

#if __has_builtin(__builtin_amdgcn_exp2f)
#define EXP2(x) __builtin_amdgcn_exp2f(x)
#else
#define EXP2(x) exp2f(x)
#endif

namespace {

constexpr int Bc = 2, Tc = 2048, Dc = 2048, Hc = 32, KVHc = 8, HDc = 64;
constexpr int NQKV = Hc * HDc + 2 * KVHc * HDc;  // 3072

typedef __bf16 bf16x8 __attribute__((ext_vector_type(8)));
typedef unsigned short u16x8 __attribute__((ext_vector_type(8)));
typedef unsigned short u16x4 __attribute__((ext_vector_type(4)));
typedef float f32x4 __attribute__((ext_vector_type(4)));

union FragU { u16x8 u; bf16x8 b; };

DI float bits2f(unsigned int u) {
  union { unsigned int i; float f; } v; v.i = u << 16; return v.f;
}
DI unsigned short f2bits(float f) {
  __hip_bfloat16 h = __float2bfloat16(f);
  return *reinterpret_cast<unsigned short*>(&h);
}

DI void store_out(float* p, float v) { *p = v; }
DI void store_out(__hip_bfloat16* p, float v) { *p = __float2bfloat16(v); }

typedef __attribute__((address_space(1))) void gv_t;
typedef __attribute__((address_space(3))) void lv_t;

// Stage TOTB bytes (tile rows of ROWB bytes, global row stride row_stride_b) into
// LDS via global_load_lds width=16. LDS dest is wave-uniform base + lane*16 (HW),
// so the optional XOR swizzle permutes the GLOBAL source chunk per lane instead:
// LDS slot (row, chunk k) holds global chunk k ^ (row&7)  [ROWB=128 only].
template<int ROWB, int TOTB, bool SWZ = false>
DI void stage_tile(const char* g, long long row_stride_b, char* lds) {
  const int tid = threadIdx.x;
  const int wid = tid >> 6, lane = tid & 63;
#pragma unroll
  for (int it = 0; it < TOTB / 4096; ++it) {
    int off = it * 4096 + wid * 1024 + lane * 16;
    int row = off / ROWB;
    int colb = off % ROWB;
    if (SWZ) colb ^= (row & 7) << 4;  // 16B-chunk XOR swizzle (ROWB=128)
    const char* gp = g + (long long)row * row_stride_b + colb;
    char* lp = lds + it * 4096 + wid * 1024;  // wave-uniform
    __builtin_amdgcn_global_load_lds((gv_t*)gp, (lv_t*)lp, 16, 0, 0);
  }
}

// ---------------- f32 -> bf16 elementwise convert (8 elems/thread) ----------------
__global__ __launch_bounds__(256) void cvt_f32_bf16(
    const float* __restrict__ in, __hip_bfloat16* __restrict__ out) {
  const long long i = ((long long)blockIdx.x * 256 + threadIdx.x) * 8;
  const float4 a = *(const float4*)(in + i);
  const float4 b = *(const float4*)(in + i + 4);
  u16x8 r;
  r[0] = f2bits(a.x); r[1] = f2bits(a.y); r[2] = f2bits(a.z); r[3] = f2bits(a.w);
  r[4] = f2bits(b.x); r[5] = f2bits(b.y); r[6] = f2bits(b.z); r[7] = f2bits(b.w);
  *(u16x8*)((unsigned short*)out + i) = r;
}

// ------------- 64x64 tiled transpose + f32->bf16 convert: out[c][r] = in[r][c] -------------
__global__ __launch_bounds__(256) void transpose_cvt_kernel(
    const float* __restrict__ in, __hip_bfloat16* __restrict__ out, int R, int C) {
  __shared__ unsigned short tile[64][65];
  const int c0 = blockIdx.x * 64, r0 = blockIdx.y * 64;
  const int tid = threadIdx.x;
  const int rr = tid >> 2, seg = (tid & 3) * 16;
  const float* src = in + (long long)(r0 + rr) * C + c0 + seg;
#pragma unroll
  for (int i = 0; i < 16; ++i) tile[rr][seg + i] = f2bits(src[i]);
  __syncthreads();
  unsigned short* dst = (unsigned short*)out + (long long)(c0 + rr) * R + r0 + seg;
#pragma unroll
  for (int i = 0; i < 16; ++i) dst[i] = tile[seg + i][rr];
}

// ---------------- 64x64 tiled bf16 transpose: out[c][r] = in[r][c] ----------------
__global__ __launch_bounds__(256) void transpose_kernel(
    const __hip_bfloat16* __restrict__ in, __hip_bfloat16* __restrict__ out,
    int R, int C) {
  __shared__ unsigned short tile[64][65];
  const long long slice = (long long)R * C;
  const unsigned short* ip = (const unsigned short*)in + (long long)blockIdx.z * slice;
  unsigned short* op = (unsigned short*)out + (long long)blockIdx.z * slice;
  const int c0 = blockIdx.x * 64, r0 = blockIdx.y * 64;
  const int tid = threadIdx.x;
  const int rr = tid >> 2, seg = (tid & 3) * 16;
  const unsigned short* src = ip + (long long)(r0 + rr) * C + c0 + seg;
#pragma unroll
  for (int i = 0; i < 16; ++i) tile[rr][seg + i] = src[i];
  __syncthreads();
  unsigned short* dst = op + (long long)(c0 + rr) * R + r0 + seg;
#pragma unroll
  for (int i = 0; i < 16; ++i) dst[i] = tile[seg + i][rr];
}

// ---------------- GEMM: C[m][n] = sum_k A[m][k]*Bt[n][k] (+bias[n]) ----------------
// A: MxK row-major bf16, Bt: NxK row-major bf16 (B pre-transposed), C: MxN (OT).
// 128x128 tile, BK=32, 4 waves in 2x2, 4x4 16x16x32 MFMAs per wave. (round-3/4 validated)
template <typename OT>
__global__ __launch_bounds__(256) void gemm_bt(
    const __hip_bfloat16* __restrict__ A, const __hip_bfloat16* __restrict__ Bt,
    const float* __restrict__ bias, OT* __restrict__ C, int M, int N, int K) {
  __shared__ __align__(16) char As[8192];  // 128 x 32 bf16
  __shared__ __align__(16) char Bs[8192];
  const int n0 = blockIdx.x * 128;
  const int m0 = blockIdx.y * 128;
  const int tid = threadIdx.x;
  const int wid = tid >> 6, lane = tid & 63;
  const int wm = (wid >> 1) * 64, wn = (wid & 1) * 64;
  const int l15 = lane & 15, quad = lane >> 4;

  f32x4 acc[4][4] = {};

  const int nk = K >> 5;
  for (int kt = 0; kt < nk; ++kt) {
    __syncthreads();  // protect LDS reuse from previous iteration's readers
    stage_tile<64, 8192>((const char*)(A + (long long)m0 * K + kt * 32), (long long)K * 2, As);
    stage_tile<64, 8192>((const char*)(Bt + (long long)n0 * K + kt * 32), (long long)K * 2, Bs);
    __syncthreads();  // drains vmcnt(0): staging complete

    FragU a[4], b[4];
#pragma unroll
    for (int mt = 0; mt < 4; ++mt)
      a[mt].u = *(const u16x8*)(As + ((wm + mt * 16 + l15) * 32 + quad * 8) * 2);
#pragma unroll
    for (int nt = 0; nt < 4; ++nt)
      b[nt].u = *(const u16x8*)(Bs + ((wn + nt * 16 + l15) * 32 + quad * 8) * 2);
#pragma unroll
    for (int mt = 0; mt < 4; ++mt)
#pragma unroll
      for (int nt = 0; nt < 4; ++nt)
        acc[mt][nt] = __builtin_amdgcn_mfma_f32_16x16x32_bf16(a[mt].b, b[nt].b, acc[mt][nt], 0, 0, 0);
  }

#pragma unroll
  for (int nt = 0; nt < 4; ++nt) {
    const int col = n0 + wn + nt * 16 + l15;
    const float bv = bias ? bias[col] : 0.f;
#pragma unroll
    for (int mt = 0; mt < 4; ++mt) {
#pragma unroll
      for (int r = 0; r < 4; ++r) {
        const int row = m0 + wm + mt * 16 + quad * 4 + r;
        store_out(C + (long long)row * N + col, acc[mt][nt][r] + bv);
      }
    }
  }
}

// ---------------- RoPE + reshape ----------------
// qkv (B*T, 3072) bf16 -> Q (B,H,T,64) roped*SCL, K (B,KVH,T,64) roped, V raw.
// SCL = (1/sqrt(64)) * log2(e) folded into Q so attention uses exp2.
__global__ __launch_bounds__(256) void rope_reshape(
    const __hip_bfloat16* __restrict__ qkv, const float* __restrict__ cosb,
    const float* __restrict__ sinb, __hip_bfloat16* __restrict__ Qo,
    __hip_bfloat16* __restrict__ Ko, __hip_bfloat16* __restrict__ Vo) {
  constexpr float SCL = 0.125f * 1.44269504088896f;
  const int row = blockIdx.x;            // b*T + t
  const int b = row / Tc, t = row % Tc;
  const unsigned short* src = (const unsigned short*)qkv + (long long)row * NQKV;
  const float* cb = cosb + t * 32;
  const float* sb = sinb + t * 32;
  unsigned short* Qp = (unsigned short*)Qo;
  unsigned short* Kp = (unsigned short*)Ko;
  unsigned short* Vp = (unsigned short*)Vo;
#pragma unroll
  for (int rep = 0; rep < 6; ++rep) {
    const int pid = rep * 256 + (int)threadIdx.x;  // pair id, 0..1535
    const int e = pid * 2;
    const unsigned int pr = *(const unsigned int*)(src + e);
    const float xe = bits2f(pr & 0xffffu);
    const float xo = bits2f(pr >> 16);
    if (e < Hc * HDc) {                         // Q section (scaled)
      const int hh = e >> 6, d = e & 63, ii = d >> 1;
      const float c = cb[ii], s = sb[ii];
      const unsigned int pk = (unsigned int)f2bits((xe * c - xo * s) * SCL) |
                              ((unsigned int)f2bits((xe * s + xo * c) * SCL) << 16);
      const long long idx = (((long long)b * Hc + hh) * Tc + t) * HDc + d;
      *(unsigned int*)(Qp + idx) = pk;
    } else if (e < Hc * HDc + KVHc * HDc) {     // K section
      const int e2 = e - Hc * HDc;
      const int kh = e2 >> 6, d = e2 & 63, ii = d >> 1;
      const float c = cb[ii], s = sb[ii];
      const unsigned int pk = (unsigned int)f2bits(xe * c - xo * s) |
                              ((unsigned int)f2bits(xe * s + xo * c) << 16);
      const long long idx = (((long long)b * KVHc + kh) * Tc + t) * HDc + d;
      *(unsigned int*)(Kp + idx) = pk;
    } else {                                    // V section (no rope)
      const int e2 = e - (Hc * HDc + KVHc * HDc);
      const int kh = e2 >> 6, d = e2 & 63;
      const long long idx = (((long long)b * KVHc + kh) * Tc + t) * HDc + d;
      *(unsigned int*)(Vp + idx) = pr;
    }
  }
}

// ---------------- Causal flash attention (S^T softmax, conservative sync) ----------------
// Q (B,H,T,64) pre-scaled by 0.125*log2e, K (B,KVH,T,64), Vt (B,KVH,64,T) -> Out (B,T,H*64).
// Block = 64 q rows of one (b,h); 4 waves, each a 16-q strip (q = wid*16 + lane&15).
// S^T = mfma(K_rows, Q_rows): lane holds 16 kv values of ONE q -> in-lane softmax
// reductions + 2 cross-quad shuffles. O^T = mfma(Vt_rows, P_rows). Base-2 online softmax.
// Sync: round-3-proven 2-barrier-per-tile; single K/V buffers; dedicated Qs buffer
// (never overwritten -> Q-hoist has no WAR hazard). No prefetch, no buffer flipping.
__global__ __launch_bounds__(256) void attn_kernel(
    const __hip_bfloat16* __restrict__ Q, const __hip_bfloat16* __restrict__ K,
    const __hip_bfloat16* __restrict__ Vt, __hip_bfloat16* __restrict__ Out) {
  __shared__ __align__(16) char Qs[8192];                  // 64 q x 64 hd (swizzled)
  __shared__ __align__(16) char Ks[8192];                  // 64 kv x 64 hd (swizzled)
  __shared__ __align__(16) char Vs[8192];                  // 64 hd x 64 kv (swizzled)
  __shared__ __align__(16) unsigned short Ps[4][1024];     // per-wave P strip 16q x 64kv (swz)

  const int qt = gridDim.x - 1 - blockIdx.x;  // longest blocks dispatched first
  const int h = blockIdx.y, b = blockIdx.z;
  const int kvh = h >> 2;  // G = 4
  const int tid = threadIdx.x, wid = tid >> 6, lane = tid & 63;
  const int l15 = lane & 15, quad = lane >> 4;
  const int sw = l15 & 7;
  const int q0 = qt * 64;

  const char* Qg = (const char*)(Q + (((long long)b * Hc + h) * Tc + q0) * HDc);
  const char* Kg = (const char*)(K + (((long long)b * KVHc + kvh) * Tc) * HDc);
  const char* Vg = (const char*)(Vt + (((long long)b * KVHc + kvh) * HDc) * Tc);

  // Stage Q into its own buffer; hoist fragments. Qs is never overwritten.
  stage_tile<128, 8192, true>(Qg, 128, Qs);
  __syncthreads();  // staging drained (compiler emits full waitcnt before s_barrier)

  FragU qa[2];
#pragma unroll
  for (int ks = 0; ks < 2; ++ks)
    qa[ks].u = *(const u16x8*)(Qs + (wid * 16 + l15) * 128 + ((((ks << 2) | quad) ^ sw) << 4));

  f32x4 Oacc[4] = {};
  float m_i = -1e30f, l_i = 0.f;  // per-lane scalars (one q per lane)

  unsigned short* Pw = &Ps[wid][0];

  for (int j = 0; j <= qt; ++j) {
    __syncthreads();  // previous iteration's Ks/Vs readers done
    stage_tile<128, 8192, true>(Kg + (long long)j * 8192, 128, Ks);
    stage_tile<128, 8192, true>(Vg + (long long)j * 128, (long long)Tc * 2, Vs);
    __syncthreads();  // staging drained

    // S^T strip (64 kv x 16 q): Sacc[nt][r] has kv = nt*16+quad*4+r, q = wid*16+l15
    f32x4 Sacc[4] = {};
#pragma unroll
    for (int nt = 0; nt < 4; ++nt) {
#pragma unroll
      for (int ks = 0; ks < 2; ++ks) {
        FragU kb;
        kb.u = *(const u16x8*)(Ks + (nt * 16 + l15) * 128 + ((((ks << 2) | quad) ^ sw) << 4));
        Sacc[nt] = __builtin_amdgcn_mfma_f32_16x16x32_bf16(kb.b, qa[ks].b, Sacc[nt], 0, 0, 0);
      }
    }

    // causal mask (wave-uniform branch; diagonal tile only)
    if (j == qt) {
#pragma unroll
      for (int nt = 0; nt < 4; ++nt)
#pragma unroll
        for (int r = 0; r < 4; ++r)
          if ((nt * 16 + quad * 4 + r) > (wid * 16 + l15)) Sacc[nt][r] = -1e30f;
    }

    // online softmax (base 2): in-lane reduce over 16 kv, then 2 cross-quad shuffles
    float mx = fmaxf(fmaxf(Sacc[0][0], Sacc[0][1]), fmaxf(Sacc[0][2], Sacc[0][3]));
#pragma unroll
    for (int nt = 1; nt < 4; ++nt)
      mx = fmaxf(mx, fmaxf(fmaxf(Sacc[nt][0], Sacc[nt][1]), fmaxf(Sacc[nt][2], Sacc[nt][3])));
    mx = fmaxf(mx, __shfl_xor(mx, 16, 64));
    mx = fmaxf(mx, __shfl_xor(mx, 32, 64));
    const float mnew = fmaxf(m_i, mx);
    const float alpha = EXP2(m_i - mnew);  // first iter: exp2(-inf) = 0
    m_i = mnew;

    float pe[4][4];
    float sum = 0.f;
#pragma unroll
    for (int nt = 0; nt < 4; ++nt)
#pragma unroll
      for (int r = 0; r < 4; ++r) {
        const float p = EXP2(Sacc[nt][r] - mnew);
        pe[nt][r] = p;
        sum += p;
      }
    sum += __shfl_xor(sum, 16, 64);
    sum += __shfl_xor(sum, 32, 64);
    l_i = l_i * alpha + sum;

    // rescale O; write P[q=l15][kv] (row-major, swizzled) to wave-private strip
#pragma unroll
    for (int nt = 0; nt < 4; ++nt)
#pragma unroll
      for (int r = 0; r < 4; ++r) {
        Oacc[nt][r] *= alpha;
        // kv = nt*16 + quad*4 + r; chunk = kv>>3 = nt*2 + (quad>>1); pos = (quad&1)*4 + r
        Pw[l15 * 64 + (((nt * 2 + (quad >> 1)) ^ sw) << 3) + ((quad & 1) << 2) + r] =
            f2bits(pe[nt][r]);
      }

    // PV: O^T = V^T (A rows: hd) x P (B rows: q). Oacc[nt][r]: hd = nt*16+quad*4+r, q = l15.
    FragU pa[2];
#pragma unroll
    for (int ks = 0; ks < 2; ++ks)
      pa[ks].u = *(const u16x8*)((const char*)Pw + l15 * 128 + ((((ks << 2) | quad) ^ sw) << 4));
#pragma unroll
    for (int nt = 0; nt < 4; ++nt) {
#pragma unroll
      for (int ks = 0; ks < 2; ++ks) {
        FragU vb;
        vb.u = *(const u16x8*)(Vs + (nt * 16 + l15) * 128 + ((((ks << 2) | quad) ^ sw) << 4));
        Oacc[nt] = __builtin_amdgcn_mfma_f32_16x16x32_bf16(vb.b, pa[ks].b, Oacc[nt], 0, 0, 0);
      }
    }
  }

  // epilogue: O^T / l -> Out[b][t][h*64+hd]; r-contiguous -> 8B stores
  const float inv_l = 1.0f / l_i;
  const int t = q0 + wid * 16 + l15;
  unsigned short* ob =
      (unsigned short*)Out + ((long long)b * Tc + t) * Dc + h * 64 + quad * 4;
#pragma unroll
  for (int nt = 0; nt < 4; ++nt) {
    u16x4 v;
#pragma unroll
    for (int r = 0; r < 4; ++r) v[r] = f2bits(Oacc[nt][r] * inv_l);
    *(u16x4*)(ob + nt * 16) = v;
  }
}

}  // namespace

extern "C" void kernel_launch(void* const* d_in, const int* in_sizes, int n_in,
                              void* d_out, int out_size, void* d_ws, size_t ws_size,
                              hipStream_t stream) {
  // All inputs/outputs are FLOAT32 per the reference dtypes.
  const float* x_q  = (const float*)d_in[0];
  const float* Wqkv = (const float*)d_in[1];
  const float* Wout = (const float*)d_in[2];
  const float* bout = (const float*)d_in[3];
  const float* rc   = (const float*)d_in[4];
  const float* rs   = (const float*)d_in[5];
  float* out = (float*)d_out;

  // ---- Overlapping bf16 workspace arena (peak 54.6 MB; stream order makes reuse safe) ----
  constexpr size_t SZ_QKV   = (size_t)Bc * Tc * NQKV * 2;        // 25,165,824
  constexpr size_t SZ_XB    = (size_t)Bc * Tc * Dc * 2;          // 16,777,216
  constexpr size_t SZ_QB    = (size_t)Bc * Hc * Tc * HDc * 2;    // 16,777,216
  constexpr size_t SZ_KV    = (size_t)Bc * KVHc * Tc * HDc * 2;  //  4,194,304
  constexpr size_t SZ_AO    = (size_t)Bc * Tc * Dc * 2;          // 16,777,216
  constexpr size_t OFF_QKV   = 0;                    //  0   .. 25.2M
  constexpr size_t OFF_XB    = SZ_QKV;               // 25.2 .. 41.9M
  constexpr size_t OFF_WQKVT = SZ_QKV + SZ_XB;       // 41.9 .. 54.6M
  constexpr size_t OFF_QB    = SZ_QKV;               // reuses xb (dead after G1)
  constexpr size_t OFF_KB    = OFF_QB + SZ_QB;       // reuses WqkvT head (dead after G1)
  constexpr size_t OFF_VTMP  = OFF_KB + SZ_KV;       // 46.1 .. 50.3M
  constexpr size_t OFF_VT    = 0;                    // reuses qkv (dead after R)
  constexpr size_t OFF_AO    = SZ_KV;                // 4.2 .. 21.0M (old qkv region)
  constexpr size_t OFF_WOUTT = OFF_AO + SZ_AO;       // 21.0 .. 29.4M (old Qb head, dead after A)

  char* w = (char*)d_ws;
  __hip_bfloat16* qkv   = (__hip_bfloat16*)(w + OFF_QKV);
  __hip_bfloat16* xb    = (__hip_bfloat16*)(w + OFF_XB);
  __hip_bfloat16* WqkvT = (__hip_bfloat16*)(w + OFF_WQKVT);
  __hip_bfloat16* Qb    = (__hip_bfloat16*)(w + OFF_QB);
  __hip_bfloat16* Kb    = (__hip_bfloat16*)(w + OFF_KB);
  __hip_bfloat16* Vtmp  = (__hip_bfloat16*)(w + OFF_VTMP);
  __hip_bfloat16* Vt    = (__hip_bfloat16*)(w + OFF_VT);
  __hip_bfloat16* AO    = (__hip_bfloat16*)(w + OFF_AO);
  __hip_bfloat16* WoutT = (__hip_bfloat16*)(w + OFF_WOUTT);

  // C1: x_q f32 -> bf16
  cvt_f32_bf16<<<dim3((Bc * Tc * Dc) / (256 * 8)), 256, 0, stream>>>(x_q, xb);

  // T1: W_qkv (D,3072) f32 -> (3072,D) bf16
  transpose_cvt_kernel<<<dim3(NQKV / 64, Dc / 64), 256, 0, stream>>>(Wqkv, WqkvT, Dc, NQKV);

  // G1: qkv = x @ W_qkv  (bf16 out)
  gemm_bt<__hip_bfloat16><<<dim3(NQKV / 128, (Bc * Tc) / 128), 256, 0, stream>>>(
      xb, WqkvT, nullptr, qkv, Bc * Tc, NQKV, Dc);

  // R: split + rope (+ Q pre-scale) + head-major layouts
  rope_reshape<<<dim3(Bc * Tc), 256, 0, stream>>>(qkv, rc, rs, Qb, Kb, Vtmp);

  // TV: V (B,KVH,T,64) -> V^T (B,KVH,64,T)
  transpose_kernel<<<dim3(HDc / 64, Tc / 64, Bc * KVHc), 256, 0, stream>>>(Vtmp, Vt, Tc, HDc);

  // A: flash attention
  attn_kernel<<<dim3(Tc / 64, Hc, Bc), 256, 0, stream>>>(Qb, Kb, Vt, AO);

  // T2: W_out f32 -> W_out^T bf16
  transpose_cvt_kernel<<<dim3(Dc / 64, Dc / 64), 256, 0, stream>>>(Wout, WoutT, Dc, Dc);

  // G2: out = AO @ W_out + b_out  (f32 out)
  gemm_bt<float><<<dim3(Dc / 128, (Bc * Tc) / 128), 256, 0, stream>>>(
      AO, WoutT, bout, out, Bc * Tc, Dc, Dc);
}